// Round 1
// baseline (1502.220 us; speedup 1.0000x reference)
//
#include <hip/hip_runtime.h>
#include <math.h>

#define EPSF 1e-6f
#define ST1 68   // LDS row stride for 64-edge tiles (16B-aligned for r0%4==0, breaks pow2 banks)
#define ST2 36   // LDS row stride for 32-edge tiles

__device__ __forceinline__ float silu_f(float x){ return x * (1.0f/(1.0f + __expf(-x))); }

// ---------------- Qnode = node_attrs @ Wq : [N,64] x [64,512] ----------------
__global__ __launch_bounds__(256) void k_qnode(
    const float* __restrict__ na, const float* __restrict__ Wq,
    float* __restrict__ qn)
{
  __shared__ float At[64*16];
  const int nb = blockIdx.x * 16;
  const int t = threadIdx.x;
  for (int f = t; f < 16*64; f += 256){ int n = f>>6, i = f&63; At[i*16+n] = na[(size_t)(nb+n)*64 + i]; }
  __syncthreads();
  float acc0[16], acc1[16];
#pragma unroll
  for (int n=0;n<16;n++){ acc0[n]=0.f; acc1[n]=0.f; }
  for (int i=0;i<64;i++){
    float w0 = Wq[(size_t)i*512 + t];
    float w1 = Wq[(size_t)i*512 + t + 256];
#pragma unroll
    for (int n=0;n<16;n++){ float a = At[i*16+n]; acc0[n] = fmaf(a,w0,acc0[n]); acc1[n] = fmaf(a,w1,acc1[n]); }
  }
#pragma unroll
  for (int n=0;n<16;n++){
    qn[(size_t)(nb+n)*512 + t]       = acc0[n];
    qn[(size_t)(nb+n)*512 + t + 256] = acc1[n];
  }
}

// ---------------- edge kernel 1: env-MLP + K-proj + logits + atomic num/denom ----------------
__global__ __launch_bounds__(256) void k_edge1(
    const float* __restrict__ ssi, const float* __restrict__ cond,
    const float* __restrict__ equiv, const int* __restrict__ esrc,
    const float* __restrict__ W1, const float* __restrict__ b1,
    const float* __restrict__ W2, const float* __restrict__ Wk,
    const float* __restrict__ qn,
    float* __restrict__ denom, float* __restrict__ num)
{
  __shared__ float sm[96*ST1 + 128*ST1];  // Xt | Ht  (~60.9 KB -> 2 blocks/CU)
  __shared__ int src_l[64];
  float* Xt = sm;                 // 96 x ST1 : [s(64) | cond(32)] transposed
  float* Ht = sm + 96*ST1;        // 128 x ST1
  float* wl = Ht;                 // alias: 64 x ST1 (after barrier, Ht dead)
  float* lg = Ht + 64*ST1;        // alias: 64 x 32 logits/exp (disjoint from wl)
  const int e0 = blockIdx.x * 64;
  const int t = threadIdx.x;
  const int r0 = (t>>5)*8;

  for (int f=t; f<64*64; f+=256){ int r=f>>6, i=f&63; Xt[i*ST1+r] = ssi[(size_t)(e0+r)*64 + i]; }
  for (int f=t; f<64*32; f+=256){ int r=f>>5, i=f&31; Xt[(64+i)*ST1+r] = cond[(size_t)(e0+r)*32 + i]; }
  if (t < 64) src_l[t] = esrc[e0+t];
  __syncthreads();

  // H = silu(X @ W_env1 + b_env1)  -> Ht
  {
    const int c0 = (t&31)*4;
    float acc[8][4];
#pragma unroll
    for (int rr=0;rr<8;rr++){ acc[rr][0]=0;acc[rr][1]=0;acc[rr][2]=0;acc[rr][3]=0; }
    for (int i=0;i<96;i++){
      const float4 w  = *(const float4*)(W1 + (size_t)i*128 + c0);
      const float4 xa = *(const float4*)(Xt + i*ST1 + r0);
      const float4 xb = *(const float4*)(Xt + i*ST1 + r0 + 4);
      const float xv[8] = {xa.x,xa.y,xa.z,xa.w,xb.x,xb.y,xb.z,xb.w};
#pragma unroll
      for (int rr=0;rr<8;rr++){
        acc[rr][0] = fmaf(xv[rr], w.x, acc[rr][0]);
        acc[rr][1] = fmaf(xv[rr], w.y, acc[rr][1]);
        acc[rr][2] = fmaf(xv[rr], w.z, acc[rr][2]);
        acc[rr][3] = fmaf(xv[rr], w.w, acc[rr][3]);
      }
    }
    const float4 bb = *(const float4*)(b1 + c0);
    const float bv[4] = {bb.x,bb.y,bb.z,bb.w};
#pragma unroll
    for (int cc=0;cc<4;cc++)
#pragma unroll
      for (int rr=0;rr<8;rr++)
        Ht[(c0+cc)*ST1 + r0+rr] = silu_f(acc[rr][cc] + bv[cc]);
  }
  __syncthreads();

  // w = H @ W_env2 (keep in regs; write to wl after barrier since wl aliases Ht)
  float wacc[8][2];
  {
    const int c0 = (t&31)*2;
#pragma unroll
    for (int rr=0;rr<8;rr++){ wacc[rr][0]=0; wacc[rr][1]=0; }
    for (int j=0;j<128;j++){
      const float2 w  = *(const float2*)(W2 + (size_t)j*64 + c0);
      const float4 ha = *(const float4*)(Ht + j*ST1 + r0);
      const float4 hb = *(const float4*)(Ht + j*ST1 + r0 + 4);
      const float hv[8] = {ha.x,ha.y,ha.z,ha.w,hb.x,hb.y,hb.z,hb.w};
#pragma unroll
      for (int rr=0;rr<8;rr++){
        wacc[rr][0] = fmaf(hv[rr], w.x, wacc[rr][0]);
        wacc[rr][1] = fmaf(hv[rr], w.y, wacc[rr][1]);
      }
    }
  }
  __syncthreads();
  {
    const int c0 = (t&31)*2;
#pragma unroll
    for (int cc=0;cc<2;cc++)
#pragma unroll
      for (int rr=0;rr<8;rr++)
        wl[(c0+cc)*ST1 + r0+rr] = wacc[rr][cc];
  }
  __syncthreads();

  // K = s @ Wk ; logits[r][m] = (K . Q[src]) ; write exp later
  for (int it=0; it<4; it++){
    const int c0 = (t&31)*4 + it*128;
    float acc[8][4];
#pragma unroll
    for (int rr=0;rr<8;rr++){ acc[rr][0]=0;acc[rr][1]=0;acc[rr][2]=0;acc[rr][3]=0; }
    for (int i=0;i<64;i++){
      const float4 w  = *(const float4*)(Wk + (size_t)i*512 + c0);
      const float4 xa = *(const float4*)(Xt + i*ST1 + r0);
      const float4 xb = *(const float4*)(Xt + i*ST1 + r0 + 4);
      const float xv[8] = {xa.x,xa.y,xa.z,xa.w,xb.x,xb.y,xb.z,xb.w};
#pragma unroll
      for (int rr=0;rr<8;rr++){
        acc[rr][0] = fmaf(xv[rr], w.x, acc[rr][0]);
        acc[rr][1] = fmaf(xv[rr], w.y, acc[rr][1]);
        acc[rr][2] = fmaf(xv[rr], w.z, acc[rr][2]);
        acc[rr][3] = fmaf(xv[rr], w.w, acc[rr][3]);
      }
    }
    const int m = c0 >> 4;
#pragma unroll
    for (int rr=0;rr<8;rr++){
      const float4 q = *(const float4*)(qn + (size_t)src_l[r0+rr]*512 + c0);
      float p = acc[rr][0]*q.x + acc[rr][1]*q.y + acc[rr][2]*q.z + acc[rr][3]*q.w;
      p += __shfl_xor(p, 1);
      p += __shfl_xor(p, 2);
      if ((t&3)==0) lg[(r0+rr)*32 + m] = p;
    }
  }
  __syncthreads();

  // exp(clip(logits/4)) + denominator atomics (no max-subtraction: logits clipped to +-5)
  for (int f=t; f<64*32; f+=256){
    int r=f>>5, m=f&31;
    float l = lg[f] * 0.25f;
    l = fminf(5.0f, fmaxf(-5.0f, l));
    float el = __expf(l);
    lg[f] = el;
    atomicAdd(denom + (size_t)src_l[r]*32 + m, el);
  }
  __syncthreads();

  // numerator atomics: num[src][m][c] += e * equiv * w_exp
  for (int f=t; f<64*128; f+=256){
    int r=f>>7, mc=f&127, m=mc>>2, c=mc&3;
    float el = lg[r*32+m];
    float wv = wl[(m*2 + (c?1:0))*ST1 + r];
    float ev = equiv[(size_t)(e0+r)*128 + mc];
    atomicAdd(num + (size_t)src_l[r]*128 + mc, el*wv*ev);
  }
}

// ---------------- per-node: attn division + env SO(3) layernorm (in place) ----------------
__global__ __launch_bounds__(128) void k_dnorm(
    float* __restrict__ num, const float* __restrict__ denom,
    const float* __restrict__ g_env)
{
  __shared__ float red[128];
  __shared__ float inv0s, inv1s;
  const int n = blockIdx.x, t = threadIdx.x;
  const int m = t>>2, c = t&3;
  const float d = denom[(size_t)n*32+m];
  const float x = (d > 0.0f) ? num[(size_t)n*128+t]/d : 0.0f;
  red[t] = x*x;
  __syncthreads();
  if (t < 32){
    float p0 = red[4*t];
    float p1 = red[4*t+1]+red[4*t+2]+red[4*t+3];
#pragma unroll
    for (int k=1;k<32;k<<=1){ p0 += __shfl_xor(p0,k); p1 += __shfl_xor(p1,k); }
    if (t==0){ inv0s = 1.0f/sqrtf(p0*(1.0f/32.0f) + EPSF); inv1s = 1.0f/sqrtf(p1*(1.0f/96.0f) + EPSF); }
  }
  __syncthreads();
  const float g = g_env[m*2 + (c?1:0)];
  num[(size_t)n*128+t] = x * (c ? inv1s : inv0s) * g;
}

// ---------------- edge kernel 2: gather env, tp + norms, p-MLP, outputs ----------------
__global__ __launch_bounds__(256) void k_edge2(
    const float* __restrict__ ssi, const float* __restrict__ cond,
    const float* __restrict__ equiv, const int* __restrict__ esrc,
    const float* __restrict__ envn, const float* __restrict__ g_tp,
    const float* __restrict__ Wp1, const float* __restrict__ bp1,
    const float* __restrict__ Wp2, const float* __restrict__ ruc,
    float* __restrict__ outs, float* __restrict__ oute)
{
  __shared__ float envl[32*128];     // gathered env_nodes rows
  __shared__ float Xp[96*ST2];       // [tpn scalars(64) | cond(32)] transposed
  __shared__ float Hp[128*ST2];
  __shared__ float inv_l[32*4];
  __shared__ int src_l[32];          // total ~49.3 KB -> 3 blocks/CU
  const int e0 = blockIdx.x * 32;
  const int t = threadIdx.x;
  if (t < 32) src_l[t] = esrc[e0+t];
  __syncthreads();
  for (int f=t; f<32*128; f+=256){ int r=f>>7, cx=f&127; envl[f] = envn[(size_t)src_l[r]*128 + cx]; }
  for (int f=t; f<32*32; f+=256){ int r=f>>5, i=f&31; Xp[(64+i)*ST2 + r] = cond[(size_t)(e0+r)*32 + i]; }
  __syncthreads();

  // 4 per-edge RMS norms of the tensor product (tp never materialized)
  {
    const int r = t>>3, sub = t&7;
    float ss0=0,ss1=0,ss2=0,ss3=0;
#pragma unroll
    for (int mm=0;mm<4;mm++){
      const int m = sub*4+mm;
      const float4 e4 = *(const float4*)(equiv + (size_t)(e0+r)*128 + 4*m);
      const float4 n4 = *(const float4*)(envl + r*128 + 4*m);
      const float tp0 = e4.x*n4.x;
      const float dv  = e4.y*n4.y + e4.z*n4.z + e4.w*n4.w;
      const float tp1 = dv*0.5773502691896258f;
      ss0 += tp0*tp0;
      ss1 += tp1*tp1;
      ss2 += e4.x*e4.x*(n4.y*n4.y + n4.z*n4.z + n4.w*n4.w);  // sum (s1*v2c)^2
      ss3 += n4.x*n4.x*(e4.y*e4.y + e4.z*e4.z + e4.w*e4.w);  // sum (v1c*s2)^2
    }
#pragma unroll
    for (int k=1;k<8;k<<=1){
      ss0 += __shfl_xor(ss0,k); ss1 += __shfl_xor(ss1,k);
      ss2 += __shfl_xor(ss2,k); ss3 += __shfl_xor(ss3,k);
    }
    if (sub == 0){
      inv_l[r*4+0] = 1.0f/sqrtf(ss0*(1.0f/32.0f) + EPSF);
      inv_l[r*4+1] = 1.0f/sqrtf(ss1*(1.0f/32.0f) + EPSF);
      inv_l[r*4+2] = 1.0f/sqrtf(ss2*(1.0f/96.0f) + EPSF);
      inv_l[r*4+3] = 1.0f/sqrtf(ss3*(1.0f/96.0f) + EPSF);
    }
  }
  __syncthreads();

  // Xp scalar cols: xp[2m]=tpn0, xp[2m+1]=tpn1
  for (int f=t; f<32*64; f+=256){
    const int r = f>>6, col = f&63, m = col>>1;
    const float4 e4 = *(const float4*)(equiv + (size_t)(e0+r)*128 + 4*m);
    const float4 n4 = *(const float4*)(envl + r*128 + 4*m);
    float v;
    if (col & 1)
      v = (e4.y*n4.y + e4.z*n4.z + e4.w*n4.w)*0.5773502691896258f * inv_l[r*4+1] * g_tp[m*4+1];
    else
      v = e4.x*n4.x * inv_l[r*4+0] * g_tp[m*4+0];
    Xp[col*ST2 + r] = v;
  }
  __syncthreads();

  // Hp = silu(Xp @ Wp1 + bp1)
  const int r0 = (t>>5)*4;
  {
    const int c0 = (t&31)*4;
    float acc[4][4];
#pragma unroll
    for (int rr=0;rr<4;rr++){acc[rr][0]=0;acc[rr][1]=0;acc[rr][2]=0;acc[rr][3]=0;}
    for (int i=0;i<96;i++){
      const float4 w  = *(const float4*)(Wp1 + (size_t)i*128 + c0);
      const float4 xa = *(const float4*)(Xp + i*ST2 + r0);
      const float xv[4] = {xa.x,xa.y,xa.z,xa.w};
#pragma unroll
      for (int rr=0;rr<4;rr++){
        acc[rr][0]=fmaf(xv[rr],w.x,acc[rr][0]);
        acc[rr][1]=fmaf(xv[rr],w.y,acc[rr][1]);
        acc[rr][2]=fmaf(xv[rr],w.z,acc[rr][2]);
        acc[rr][3]=fmaf(xv[rr],w.w,acc[rr][3]);
      }
    }
    const float4 bb = *(const float4*)(bp1 + c0);
    const float bv[4] = {bb.x,bb.y,bb.z,bb.w};
#pragma unroll
    for (int cc=0;cc<4;cc++)
#pragma unroll
      for (int rr=0;rr<4;rr++)
        Hp[(c0+cc)*ST2 + r0+rr] = silu_f(acc[rr][cc] + bv[cc]);
  }
  __syncthreads();

  const float rv = ruc[0];
  const float c_old = 1.0f/sqrtf(rv*rv + 1.0f);
  const float c_new = rv * c_old;

  // op[:, :64] = new_scalar  ->  scalar_out with residual
  {
    const int c0 = (t&31)*2;
    float acc[4][2];
#pragma unroll
    for (int rr=0;rr<4;rr++){acc[rr][0]=0;acc[rr][1]=0;}
    for (int j=0;j<128;j++){
      const float2 w  = *(const float2*)(Wp2 + (size_t)j*192 + c0);
      const float4 ha = *(const float4*)(Hp + j*ST2 + r0);
      const float hv[4] = {ha.x,ha.y,ha.z,ha.w};
#pragma unroll
      for (int rr=0;rr<4;rr++){
        acc[rr][0]=fmaf(hv[rr],w.x,acc[rr][0]);
        acc[rr][1]=fmaf(hv[rr],w.y,acc[rr][1]);
      }
    }
#pragma unroll
    for (int rr=0;rr<4;rr++){
      const size_t e = (size_t)(e0+r0+rr);
#pragma unroll
      for (int cc=0;cc<2;cc++)
        outs[e*64 + c0+cc] = c_old*ssi[e*64 + c0+cc] + c_new*acc[rr][cc];
    }
  }

  // op[:, 64:] = pw[m][0..3] -> equiv_out with residual (thread t owns mul m = t&31)
  {
    const int m = t&31;
    float acc[4][4];
#pragma unroll
    for (int rr=0;rr<4;rr++){acc[rr][0]=0;acc[rr][1]=0;acc[rr][2]=0;acc[rr][3]=0;}
    for (int j=0;j<128;j++){
      const float4 w  = *(const float4*)(Wp2 + (size_t)j*192 + 64 + 4*m);
      const float4 ha = *(const float4*)(Hp + j*ST2 + r0);
      const float hv[4] = {ha.x,ha.y,ha.z,ha.w};
#pragma unroll
      for (int rr=0;rr<4;rr++){
        acc[rr][0]=fmaf(hv[rr],w.x,acc[rr][0]);
        acc[rr][1]=fmaf(hv[rr],w.y,acc[rr][1]);
        acc[rr][2]=fmaf(hv[rr],w.z,acc[rr][2]);
        acc[rr][3]=fmaf(hv[rr],w.w,acc[rr][3]);
      }
    }
    const float g2 = g_tp[m*4+2], g3 = g_tp[m*4+3];
#pragma unroll
    for (int rr=0;rr<4;rr++){
      const int r = r0+rr;
      const size_t e = (size_t)(e0+r);
      const float4 e4 = *(const float4*)(equiv + e*128 + 4*m);
      const float4 n4 = *(const float4*)(envl + r*128 + 4*m);
      const float tpn0 = Xp[(2*m)*ST2 + r];
      const float tpn1 = Xp[(2*m+1)*ST2 + r];
      const float a2 = acc[rr][2]*inv_l[r*4+2]*g2;  // pw2 * inv2 * g2, times (s1*v2c)
      const float a3 = acc[rr][3]*inv_l[r*4+3]*g3;  // pw3 * inv3 * g3, times (v1c*s2)
      float4 o;
      o.x = c_old*e4.x + c_new*(acc[rr][0]*tpn0 + acc[rr][1]*tpn1);
      o.y = c_old*e4.y + c_new*(a2*(e4.x*n4.y) + a3*(e4.y*n4.x));
      o.z = c_old*e4.z + c_new*(a2*(e4.x*n4.z) + a3*(e4.z*n4.x));
      o.w = c_old*e4.w + c_new*(a2*(e4.x*n4.w) + a3*(e4.w*n4.x));
      *(float4*)(oute + e*128 + 4*m) = o;
    }
  }
}

extern "C" void kernel_launch(void* const* d_in, const int* in_sizes, int n_in,
                              void* d_out, int out_size, void* d_ws, size_t ws_size,
                              hipStream_t stream)
{
  const float* na   = (const float*)d_in[0];   // node_attrs [N,64]
  const float* ssi  = (const float*)d_in[1];   // scalar_state [E,64]
  const float* eqv  = (const float*)d_in[2];   // equiv_state [E,32,4]
  const float* cond = (const float*)d_in[3];   // edge_conditioning [E,32]
  const float* ruc  = (const float*)d_in[4];   // residual_update_coeff [1]
  const float* W1   = (const float*)d_in[5];   // W_env1 [96,128]
  const float* b1   = (const float*)d_in[6];   // b_env1 [128]
  const float* W2   = (const float*)d_in[7];   // W_env2 [128,64]
  const float* Wq   = (const float*)d_in[8];   // [64,512]
  const float* Wk   = (const float*)d_in[9];   // [64,512]
  const float* ge   = (const float*)d_in[10];  // g_env [32,2]
  const float* gt   = (const float*)d_in[11];  // g_tp [32,4]
  const float* Wp1  = (const float*)d_in[12];  // [96,128]
  const float* bp1  = (const float*)d_in[13];  // [128]
  const float* Wp2  = (const float*)d_in[14];  // [128,192]
  const int*   esrc = (const int*)d_in[15];    // edge_src [E]

  const int N = in_sizes[0] / 64;
  const int E = in_sizes[1] / 64;

  float* denom = (float*)d_ws;                 // N*32
  float* num   = denom + (size_t)N*32;         // N*128  (becomes env_nodes)
  float* qn    = num   + (size_t)N*128;        // N*512
  float* outs  = (float*)d_out;                // scalar_out [E,64]
  float* oute  = outs + (size_t)E*64;          // equiv_out [E,32,4]

  hipMemsetAsync(d_ws, 0, (size_t)N*160*sizeof(float), stream);
  k_qnode<<<N/16, 256, 0, stream>>>(na, Wq, qn);
  k_edge1<<<E/64, 256, 0, stream>>>(ssi, cond, eqv, esrc, W1, b1, W2, Wk, qn, denom, num);
  k_dnorm<<<N, 128, 0, stream>>>(num, denom, ge);
  k_edge2<<<E/32, 256, 0, stream>>>(ssi, cond, eqv, esrc, num, gt, Wp1, bp1, Wp2, ruc, outs, oute);
}

// Round 2
// 1398.516 us; speedup vs baseline: 1.0742x; 1.0742x over previous
//
#include <hip/hip_runtime.h>
#include <math.h>

#define EPSF 1e-6f
#define STX 100   // row stride for X tiles (96 data cols, pad to 100: 16B-aligned, breaks pow2)
#define STH 132   // row stride for H tiles (128 data cols)

__device__ __forceinline__ float silu_f(float x){ return x * (1.0f/(1.0f + __expf(-x))); }

// ---------------- Qnode = node_attrs @ Wq : [N,64] x [64,512] ----------------
__global__ __launch_bounds__(256) void k_qnode(
    const float* __restrict__ na, const float* __restrict__ Wq,
    float* __restrict__ qn)
{
  __shared__ float At[64*16];
  const int nb = blockIdx.x * 16;
  const int t = threadIdx.x;
  for (int f = t; f < 16*64; f += 256){ int n = f>>6, i = f&63; At[i*16+n] = na[(size_t)(nb+n)*64 + i]; }
  __syncthreads();
  float acc0[16], acc1[16];
#pragma unroll
  for (int n=0;n<16;n++){ acc0[n]=0.f; acc1[n]=0.f; }
  for (int i=0;i<64;i++){
    float w0 = Wq[(size_t)i*512 + t];
    float w1 = Wq[(size_t)i*512 + t + 256];
#pragma unroll
    for (int n=0;n<16;n++){ float a = At[i*16+n]; acc0[n] = fmaf(a,w0,acc0[n]); acc1[n] = fmaf(a,w1,acc1[n]); }
  }
#pragma unroll
  for (int n=0;n<16;n++){
    qn[(size_t)(nb+n)*512 + t]       = acc0[n];
    qn[(size_t)(nb+n)*512 + t + 256] = acc1[n];
  }
}

// ---------------- edge kernel 1: env-MLP + K-proj + logits + atomic num/denom ----------------
// 32-edge tile, row-major LDS: all LDS reads are wave-broadcasts, all writes consecutive-lane b128.
__global__ __launch_bounds__(256,4) void k_edge1(
    const float* __restrict__ ssi, const float* __restrict__ cond,
    const float* __restrict__ equiv, const int* __restrict__ esrc,
    const float* __restrict__ W1, const float* __restrict__ b1,
    const float* __restrict__ W2, const float* __restrict__ Wk,
    const float* __restrict__ qn,
    float* __restrict__ denom, float* __restrict__ num)
{
  __shared__ float Xs[32*STX];   // 12.8 KB  [r][ s(64) | cond(32) ]
  __shared__ float Hs[32*STH];   // 16.9 KB
  __shared__ float lg[32*32];    // 4 KB
  __shared__ int src_l[32];      // total ~33.1 KB -> 4 blocks/CU
  const int e0 = blockIdx.x * 32;
  const int t = threadIdx.x;
  const int r0 = (t>>5)*4;

  if (t < 32) src_l[t] = esrc[e0+t];
  for (int f=t; f<512; f+=256){ int r=f>>4, q=(f&15)*4;
    *(float4*)(Xs + r*STX + q) = *(const float4*)(ssi + (size_t)(e0+r)*64 + q); }
  { int f=t; int r=f>>3, q=(f&7)*4;
    *(float4*)(Xs + r*STX + 64 + q) = *(const float4*)(cond + (size_t)(e0+r)*32 + q); }
  __syncthreads();

  // H = silu(X @ W_env1 + b_env1)
  {
    const int c0 = (t&31)*4;
    float acc[4][4] = {};
    for (int i0=0;i0<96;i0+=4){
      float4 wv[4], xv[4];
#pragma unroll
      for (int k=0;k<4;k++) wv[k] = *(const float4*)(W1 + (size_t)(i0+k)*128 + c0);
#pragma unroll
      for (int rr=0;rr<4;rr++) xv[rr] = *(const float4*)(Xs + (r0+rr)*STX + i0);
#pragma unroll
      for (int rr=0;rr<4;rr++){
        const float xs[4] = {xv[rr].x,xv[rr].y,xv[rr].z,xv[rr].w};
#pragma unroll
        for (int k=0;k<4;k++){
          acc[rr][0] = fmaf(xs[k], wv[k].x, acc[rr][0]);
          acc[rr][1] = fmaf(xs[k], wv[k].y, acc[rr][1]);
          acc[rr][2] = fmaf(xs[k], wv[k].z, acc[rr][2]);
          acc[rr][3] = fmaf(xs[k], wv[k].w, acc[rr][3]);
        }
      }
    }
    const float4 bb = *(const float4*)(b1 + c0);
#pragma unroll
    for (int rr=0;rr<4;rr++){
      float4 h;
      h.x = silu_f(acc[rr][0]+bb.x); h.y = silu_f(acc[rr][1]+bb.y);
      h.z = silu_f(acc[rr][2]+bb.z); h.w = silu_f(acc[rr][3]+bb.w);
      *(float4*)(Hs + (r0+rr)*STH + c0) = h;
    }
  }
  __syncthreads();

  // w = H @ W_env2 (regs), then park in wl (aliases Hs after barrier)
  float wacc[4][2] = {};
  {
    const int c0 = (t&31)*2;
    for (int j0=0;j0<128;j0+=4){
      float2 w2[4]; float4 hv[4];
#pragma unroll
      for (int k=0;k<4;k++) w2[k] = *(const float2*)(W2 + (size_t)(j0+k)*64 + c0);
#pragma unroll
      for (int rr=0;rr<4;rr++) hv[rr] = *(const float4*)(Hs + (r0+rr)*STH + j0);
#pragma unroll
      for (int rr=0;rr<4;rr++){
        const float hs[4] = {hv[rr].x,hv[rr].y,hv[rr].z,hv[rr].w};
#pragma unroll
        for (int k=0;k<4;k++){
          wacc[rr][0] = fmaf(hs[k], w2[k].x, wacc[rr][0]);
          wacc[rr][1] = fmaf(hs[k], w2[k].y, wacc[rr][1]);
        }
      }
    }
  }
  __syncthreads();
  float* wl = Hs;  // 32 x 66 row-major
  {
    const int c0 = (t&31)*2;
#pragma unroll
    for (int rr=0;rr<4;rr++)
      *(float2*)(wl + (r0+rr)*66 + c0) = make_float2(wacc[rr][0], wacc[rr][1]);
  }

  // K = s @ Wk ; logits[r][m] = K . Q[src]
  for (int it=0; it<4; it++){
    const int c0k = (t&31)*4 + it*128;
    float acc[4][4] = {};
    for (int i0=0;i0<64;i0+=4){
      float4 wv[4], xv[4];
#pragma unroll
      for (int k=0;k<4;k++) wv[k] = *(const float4*)(Wk + (size_t)(i0+k)*512 + c0k);
#pragma unroll
      for (int rr=0;rr<4;rr++) xv[rr] = *(const float4*)(Xs + (r0+rr)*STX + i0);
#pragma unroll
      for (int rr=0;rr<4;rr++){
        const float xs[4] = {xv[rr].x,xv[rr].y,xv[rr].z,xv[rr].w};
#pragma unroll
        for (int k=0;k<4;k++){
          acc[rr][0] = fmaf(xs[k], wv[k].x, acc[rr][0]);
          acc[rr][1] = fmaf(xs[k], wv[k].y, acc[rr][1]);
          acc[rr][2] = fmaf(xs[k], wv[k].z, acc[rr][2]);
          acc[rr][3] = fmaf(xs[k], wv[k].w, acc[rr][3]);
        }
      }
    }
    const int m = ((t&31)>>2) + it*8;
#pragma unroll
    for (int rr=0;rr<4;rr++){
      const float4 q = *(const float4*)(qn + (size_t)src_l[r0+rr]*512 + c0k);
      float p = acc[rr][0]*q.x + acc[rr][1]*q.y + acc[rr][2]*q.z + acc[rr][3]*q.w;
      p += __shfl_xor(p, 1);
      p += __shfl_xor(p, 2);
      if ((t&3)==0) lg[(r0+rr)*32 + m] = p;
    }
  }
  __syncthreads();

  // exp(clip(logits*INV_SQRTD)) + denominator atomics (clip makes max-subtraction unnecessary)
  for (int f=t; f<1024; f+=256){
    int r=f>>5, m=f&31;
    float l = lg[f] * 0.25f;
    l = fminf(5.0f, fmaxf(-5.0f, l));
    float el = __expf(l);
    lg[f] = el;
    atomicAdd(denom + (size_t)src_l[r]*32 + m, el);
  }
  __syncthreads();

  // numerator atomics: num[src][m][c] += e * w_exp * equiv
  for (int f=t; f<1024; f+=256){
    int r=f>>5, m=f&31;
    const float el = lg[r*32+m];
    const float w0 = wl[r*66 + 2*m]   * el;
    const float w1 = wl[r*66 + 2*m+1] * el;
    const float4 ev = *(const float4*)(equiv + ((size_t)(e0+r)*32 + m)*4);
    float* np = num + (size_t)src_l[r]*128 + 4*m;
    atomicAdd(np+0, w0*ev.x);
    atomicAdd(np+1, w1*ev.y);
    atomicAdd(np+2, w1*ev.z);
    atomicAdd(np+3, w1*ev.w);
  }
}

// ---------------- per-node: attn division + env SO(3) layernorm (in place) ----------------
__global__ __launch_bounds__(128) void k_dnorm(
    float* __restrict__ num, const float* __restrict__ denom,
    const float* __restrict__ g_env)
{
  __shared__ float red[128];
  __shared__ float inv0s, inv1s;
  const int n = blockIdx.x, t = threadIdx.x;
  const int m = t>>2, c = t&3;
  const float d = denom[(size_t)n*32+m];
  const float x = (d > 0.0f) ? num[(size_t)n*128+t]/d : 0.0f;
  red[t] = x*x;
  __syncthreads();
  if (t < 32){
    float p0 = red[4*t];
    float p1 = red[4*t+1]+red[4*t+2]+red[4*t+3];
#pragma unroll
    for (int k=1;k<32;k<<=1){ p0 += __shfl_xor(p0,k); p1 += __shfl_xor(p1,k); }
    if (t==0){ inv0s = 1.0f/sqrtf(p0*(1.0f/32.0f) + EPSF); inv1s = 1.0f/sqrtf(p1*(1.0f/96.0f) + EPSF); }
  }
  __syncthreads();
  const float g = g_env[m*2 + (c?1:0)];
  num[(size_t)n*128+t] = x * (c ? inv1s : inv0s) * g;
}

// ---------------- edge kernel 2: gather env, tp + norms, p-MLP, outputs ----------------
__global__ __launch_bounds__(256,3) void k_edge2(
    const float* __restrict__ ssi, const float* __restrict__ cond,
    const float* __restrict__ equiv, const int* __restrict__ esrc,
    const float* __restrict__ envn, const float* __restrict__ g_tp,
    const float* __restrict__ Wp1, const float* __restrict__ bp1,
    const float* __restrict__ Wp2, const float* __restrict__ ruc,
    float* __restrict__ outs, float* __restrict__ oute)
{
  __shared__ float envl[32*STH];   // 16.9 KB gathered env rows (stride 132 kills 16-bank aliasing)
  __shared__ float Xp[32*STX];     // 12.8 KB [r][ tpn(64) | cond(32) ]
  __shared__ float Hp[32*STH];     // 16.9 KB
  __shared__ float inv_l[32*4];
  __shared__ int src_l[32];        // total ~47 KB -> 3 blocks/CU
  const int e0 = blockIdx.x * 32;
  const int t = threadIdx.x;
  const int r0 = (t>>5)*4;
  if (t < 32) src_l[t] = esrc[e0+t];
  __syncthreads();
  for (int f=t; f<1024; f+=256){ int r=f>>5, q=(f&31)*4;
    *(float4*)(envl + r*STH + q) = *(const float4*)(envn + (size_t)src_l[r]*128 + q); }
  { int f=t; int r=f>>3, q=(f&7)*4;
    *(float4*)(Xp + r*STX + 64 + q) = *(const float4*)(cond + (size_t)(e0+r)*32 + q); }
  __syncthreads();

  // 4 per-edge RMS norms of the tensor product (tp never materialized)
  {
    const int r = t>>3, sub = t&7;
    float ss0=0,ss1=0,ss2=0,ss3=0;
#pragma unroll
    for (int mm=0;mm<4;mm++){
      const int m = sub*4+mm;
      const float4 e4 = *(const float4*)(equiv + ((size_t)(e0+r)*32 + m)*4);
      const float4 n4 = *(const float4*)(envl + r*STH + 4*m);
      const float tp0 = e4.x*n4.x;
      const float dv  = e4.y*n4.y + e4.z*n4.z + e4.w*n4.w;
      const float tp1 = dv*0.5773502691896258f;
      ss0 += tp0*tp0;
      ss1 += tp1*tp1;
      ss2 += e4.x*e4.x*(n4.y*n4.y + n4.z*n4.z + n4.w*n4.w);
      ss3 += n4.x*n4.x*(e4.y*e4.y + e4.z*e4.z + e4.w*e4.w);
    }
#pragma unroll
    for (int k=1;k<8;k<<=1){
      ss0 += __shfl_xor(ss0,k); ss1 += __shfl_xor(ss1,k);
      ss2 += __shfl_xor(ss2,k); ss3 += __shfl_xor(ss3,k);
    }
    if (sub == 0){
      inv_l[r*4+0] = 1.0f/sqrtf(ss0*(1.0f/32.0f) + EPSF);
      inv_l[r*4+1] = 1.0f/sqrtf(ss1*(1.0f/32.0f) + EPSF);
      inv_l[r*4+2] = 1.0f/sqrtf(ss2*(1.0f/96.0f) + EPSF);
      inv_l[r*4+3] = 1.0f/sqrtf(ss3*(1.0f/96.0f) + EPSF);
    }
  }
  __syncthreads();

  // Xp scalar cols: xp[2m]=tpn0, xp[2m+1]=tpn1
  for (int f=t; f<2048; f+=256){
    const int r = f>>6, col = f&63, m = col>>1;
    const float4 e4 = *(const float4*)(equiv + ((size_t)(e0+r)*32 + m)*4);
    const float4 n4 = *(const float4*)(envl + r*STH + 4*m);
    float v;
    if (col & 1)
      v = (e4.y*n4.y + e4.z*n4.z + e4.w*n4.w)*0.5773502691896258f * inv_l[r*4+1] * g_tp[m*4+1];
    else
      v = e4.x*n4.x * inv_l[r*4+0] * g_tp[m*4+0];
    Xp[r*STX + col] = v;
  }
  __syncthreads();

  // Hp = silu(Xp @ Wp1 + bp1)
  {
    const int c0 = (t&31)*4;
    float acc[4][4] = {};
    for (int i0=0;i0<96;i0+=4){
      float4 wv[4], xv[4];
#pragma unroll
      for (int k=0;k<4;k++) wv[k] = *(const float4*)(Wp1 + (size_t)(i0+k)*128 + c0);
#pragma unroll
      for (int rr=0;rr<4;rr++) xv[rr] = *(const float4*)(Xp + (r0+rr)*STX + i0);
#pragma unroll
      for (int rr=0;rr<4;rr++){
        const float xs[4] = {xv[rr].x,xv[rr].y,xv[rr].z,xv[rr].w};
#pragma unroll
        for (int k=0;k<4;k++){
          acc[rr][0] = fmaf(xs[k], wv[k].x, acc[rr][0]);
          acc[rr][1] = fmaf(xs[k], wv[k].y, acc[rr][1]);
          acc[rr][2] = fmaf(xs[k], wv[k].z, acc[rr][2]);
          acc[rr][3] = fmaf(xs[k], wv[k].w, acc[rr][3]);
        }
      }
    }
    const float4 bb = *(const float4*)(bp1 + c0);
#pragma unroll
    for (int rr=0;rr<4;rr++){
      float4 h;
      h.x = silu_f(acc[rr][0]+bb.x); h.y = silu_f(acc[rr][1]+bb.y);
      h.z = silu_f(acc[rr][2]+bb.z); h.w = silu_f(acc[rr][3]+bb.w);
      *(float4*)(Hp + (r0+rr)*STH + c0) = h;
    }
  }
  __syncthreads();

  const float rv = ruc[0];
  const float c_old = 1.0f/sqrtf(rv*rv + 1.0f);
  const float c_new = rv * c_old;

  // op[:, :64] = new_scalar -> scalar_out with residual
  {
    const int c0 = (t&31)*2;
    float acc[4][2] = {};
    for (int j0=0;j0<128;j0+=4){
      float2 w2[4]; float4 hv[4];
#pragma unroll
      for (int k=0;k<4;k++) w2[k] = *(const float2*)(Wp2 + (size_t)(j0+k)*192 + c0);
#pragma unroll
      for (int rr=0;rr<4;rr++) hv[rr] = *(const float4*)(Hp + (r0+rr)*STH + j0);
#pragma unroll
      for (int rr=0;rr<4;rr++){
        const float hs[4] = {hv[rr].x,hv[rr].y,hv[rr].z,hv[rr].w};
#pragma unroll
        for (int k=0;k<4;k++){
          acc[rr][0] = fmaf(hs[k], w2[k].x, acc[rr][0]);
          acc[rr][1] = fmaf(hs[k], w2[k].y, acc[rr][1]);
        }
      }
    }
#pragma unroll
    for (int rr=0;rr<4;rr++){
      const size_t e = (size_t)(e0+r0+rr);
      const float2 s2 = *(const float2*)(ssi + e*64 + c0);
      float2 o2; o2.x = c_old*s2.x + c_new*acc[rr][0]; o2.y = c_old*s2.y + c_new*acc[rr][1];
      *(float2*)(outs + e*64 + c0) = o2;
    }
  }

  // op[:, 64:] = pw[m][0..3] -> equiv_out with residual (thread owns mul m = t&31)
  {
    const int m = t&31;
    float acc[4][4] = {};
    for (int j0=0;j0<128;j0+=4){
      float4 w4[4]; float4 hv[4];
#pragma unroll
      for (int k=0;k<4;k++) w4[k] = *(const float4*)(Wp2 + (size_t)(j0+k)*192 + 64 + 4*m);
#pragma unroll
      for (int rr=0;rr<4;rr++) hv[rr] = *(const float4*)(Hp + (r0+rr)*STH + j0);
#pragma unroll
      for (int rr=0;rr<4;rr++){
        const float hs[4] = {hv[rr].x,hv[rr].y,hv[rr].z,hv[rr].w};
#pragma unroll
        for (int k=0;k<4;k++){
          acc[rr][0] = fmaf(hs[k], w4[k].x, acc[rr][0]);
          acc[rr][1] = fmaf(hs[k], w4[k].y, acc[rr][1]);
          acc[rr][2] = fmaf(hs[k], w4[k].z, acc[rr][2]);
          acc[rr][3] = fmaf(hs[k], w4[k].w, acc[rr][3]);
        }
      }
    }
    const float g2 = g_tp[m*4+2], g3 = g_tp[m*4+3];
#pragma unroll
    for (int rr=0;rr<4;rr++){
      const int r = r0+rr;
      const size_t e = (size_t)(e0+r);
      const float4 e4 = *(const float4*)(equiv + (e*32 + m)*4);
      const float4 n4 = *(const float4*)(envl + r*STH + 4*m);
      const float tpn0 = Xp[r*STX + 2*m];
      const float tpn1 = Xp[r*STX + 2*m+1];
      const float a2 = acc[rr][2]*inv_l[r*4+2]*g2;
      const float a3 = acc[rr][3]*inv_l[r*4+3]*g3;
      float4 o;
      o.x = c_old*e4.x + c_new*(acc[rr][0]*tpn0 + acc[rr][1]*tpn1);
      o.y = c_old*e4.y + c_new*(a2*(e4.x*n4.y) + a3*(e4.y*n4.x));
      o.z = c_old*e4.z + c_new*(a2*(e4.x*n4.z) + a3*(e4.z*n4.x));
      o.w = c_old*e4.w + c_new*(a2*(e4.x*n4.w) + a3*(e4.w*n4.x));
      *(float4*)(oute + e*128 + 4*m) = o;
    }
  }
}

extern "C" void kernel_launch(void* const* d_in, const int* in_sizes, int n_in,
                              void* d_out, int out_size, void* d_ws, size_t ws_size,
                              hipStream_t stream)
{
  const float* na   = (const float*)d_in[0];
  const float* ssi  = (const float*)d_in[1];
  const float* eqv  = (const float*)d_in[2];
  const float* cond = (const float*)d_in[3];
  const float* ruc  = (const float*)d_in[4];
  const float* W1   = (const float*)d_in[5];
  const float* b1   = (const float*)d_in[6];
  const float* W2   = (const float*)d_in[7];
  const float* Wq   = (const float*)d_in[8];
  const float* Wk   = (const float*)d_in[9];
  const float* ge   = (const float*)d_in[10];
  const float* gt   = (const float*)d_in[11];
  const float* Wp1  = (const float*)d_in[12];
  const float* bp1  = (const float*)d_in[13];
  const float* Wp2  = (const float*)d_in[14];
  const int*   esrc = (const int*)d_in[15];

  const int N = in_sizes[0] / 64;
  const int E = in_sizes[1] / 64;

  float* denom = (float*)d_ws;                 // N*32
  float* num   = denom + (size_t)N*32;         // N*128 (becomes env_nodes)
  float* qn    = num   + (size_t)N*128;        // N*512
  float* outs  = (float*)d_out;                // scalar_out [E,64]
  float* oute  = outs + (size_t)E*64;          // equiv_out [E,32,4]

  hipMemsetAsync(d_ws, 0, (size_t)N*160*sizeof(float), stream);
  k_qnode<<<N/16, 256, 0, stream>>>(na, Wq, qn);
  k_edge1<<<E/32, 256, 0, stream>>>(ssi, cond, eqv, esrc, W1, b1, W2, Wk, qn, denom, num);
  k_dnorm<<<N, 128, 0, stream>>>(num, denom, ge);
  k_edge2<<<E/32, 256, 0, stream>>>(ssi, cond, eqv, esrc, num, gt, Wp1, bp1, Wp2, ruc, outs, oute);
}